// Round 3
// baseline (2299.923 us; speedup 1.0000x reference)
//
#include <hip/hip_runtime.h>
#include <hip/hip_bf16.h>

// FP8Linear: emulated-fp8 quantize (scale=1) of x[M,K] and w[N,K], then
// out[M,N] = Xq @ Wq^T + bias, f32.
// Quantized values have <=4 significant bits -> exact in bf16.
// Pass 1: quantize f32 -> bf16 into d_ws.
// Pass 2: bf16 MFMA GEMM, 256x256 tile, BK=64, 8 waves (2Mx4N), 2-dbuf
// 128KB LDS, TRUE 8-phase/2-K-tile schedule with counted vmcnt(6) (never 0
// mid-loop), half-tile staging in retirement-legal slots, XOR-swizzled LDS,
// setprio MFMA clusters, XCD block swizzle.

typedef short bf16x8 __attribute__((ext_vector_type(8)));
typedef float f32x4 __attribute__((ext_vector_type(4)));

#define BM 256
#define BN 256
#define BK 64

__device__ __forceinline__ unsigned short quant1(float v) {
    float s = fminf(fmaxf(v, -448.0f), 448.0f);
    float e = floorf(log2f(fabsf(s) + 1e-10f));
    float m = exp2f(e - 3.0f);
    float q = rintf(s / m) * m;
    return (unsigned short)(__float_as_uint(q) >> 16);  // exact: <=4 sig bits
}

__global__ __launch_bounds__(256) void quant_kernel(
    const float4* __restrict__ in, ushort4* __restrict__ out, int n4) {
    int i = blockIdx.x * blockDim.x + threadIdx.x;
    if (i >= n4) return;
    float4 v = in[i];
    ushort4 r;
    r.x = quant1(v.x);
    r.y = quant1(v.y);
    r.z = quant1(v.z);
    r.w = quant1(v.w);
    out[i] = r;
}

__device__ __forceinline__ void gload_lds16(const void* g, void* l) {
    __builtin_amdgcn_global_load_lds(
        (const __attribute__((address_space(1))) void*)g,
        (__attribute__((address_space(3))) void*)l,
        16, 0, 0);
}

// Swizzled fragment read: logical (row,col) -> lds[row*64 + (col ^ sw)],
// sw = (lane&7)<<3 (== (row&7)<<3 for all fragment rows: row = base16 + rl).
__device__ __forceinline__ bf16x8 frag_ld(const short* base, int row, int col, int sw) {
    return *(const bf16x8*)(base + (row << 6) + (col ^ sw));
}

template <int MH, int NH>
__device__ __forceinline__ void mfma_phase(f32x4 (&acc)[8][4], const bf16x8 (&af)[4][2],
                                           const bf16x8 (&bf)[2][2][2]) {
#pragma unroll
    for (int mi = 0; mi < 4; ++mi)
#pragma unroll
        for (int n = 0; n < 2; ++n)
#pragma unroll
            for (int kk = 0; kk < 2; ++kk)
                acc[MH * 4 + mi][NH * 2 + n] = __builtin_amdgcn_mfma_f32_16x16x32_bf16(
                    af[mi][kk], bf[NH][n][kk], acc[MH * 4 + mi][NH * 2 + n], 0, 0, 0);
}

#define LGKM0_SB                                         \
    asm volatile("s_waitcnt lgkmcnt(0)" ::: "memory");   \
    __builtin_amdgcn_sched_barrier(0)

// A: Xq [M][K], B: Wq [N][K] (bf16 as short), C: [M][N] f32
__global__ __launch_bounds__(512, 2) void gemm8p(
    const short* __restrict__ A, const short* __restrict__ B,
    const float* __restrict__ bias, float* __restrict__ C,
    int M, int N, int K) {
    extern __shared__ short lds[];
    // buf0: A0 [0,16384) B0 [16384,32768); buf1: A1 [32768,...) B1 [49152,...)
    short* const ldsA0 = lds;
    short* const ldsB0 = lds + 16384;
    short* const ldsA1 = lds + 32768;
    short* const ldsB1 = lds + 49152;

    const int tid = threadIdx.x;
    const int lane = tid & 63;
    const int wave = tid >> 6;
    const int wr = wave >> 2;   // 0..1 -> 128 rows each
    const int wc = wave & 3;    // 0..3 -> 64 cols each

    // XCD-aware bijective block swizzle (nwg % 8 == 0)
    const int nwg = gridDim.x;
    const int per = nwg >> 3;
    const int bid = blockIdx.x;
    const int wg = (bid & 7) * per + (bid >> 3);
    const int mtiles = M / BM;
    const int bm = wg % mtiles;
    const int bn = wg / mtiles;

    const int arow0 = bm * BM, brow0 = bn * BN;
    const int NT = K / BK;  // 64, even

    const int rl = lane & 15;
    const int kg = (lane >> 4) << 3;
    const int sw = (lane & 7) << 3;
    const int arb = wr * 128 + rl;
    const int brb = wc * 64 + rl;

    const short* const Aglob = A + (size_t)arow0 * K;
    const short* const Bglob = B + (size_t)brow0 * K;

    // per-thread staging addressing: e(c) = c*4096 + tid*8 within a half-tile
    // row(c) = c*64 + (tid>>3), col = ((tid&7)^((tid>>3)&7))<<3 (swz inverse)
    const int col0 = (((tid & 7) ^ ((tid >> 3) & 7)) << 3);
    const size_t tsrc = (size_t)(tid >> 3) * K + col0;
    const int tdst = tid * 8;

    auto stage = [&](const short* Gp, short* Lp, int region, int kt) {
#pragma unroll
        for (int c = 0; c < 2; ++c) {
            gload_lds16(Gp + (size_t)(region * 128 + c * 64) * K + kt + tsrc,
                        Lp + region * 8192 + c * 4096 + tdst);
        }
    };

    f32x4 acc[8][4] = {};
    bf16x8 af[4][2];
    bf16x8 bf[2][2][2];

    auto readAF = [&](const short* Ab, int mh) {
#pragma unroll
        for (int mi = 0; mi < 4; ++mi)
#pragma unroll
            for (int kk = 0; kk < 2; ++kk)
                af[mi][kk] = frag_ld(Ab, arb + (mh * 4 + mi) * 16, kk * 32 + kg, sw);
    };
    auto readBF = [&](const short* Bb, int nh) {
#pragma unroll
        for (int n = 0; n < 2; ++n)
#pragma unroll
            for (int kk = 0; kk < 2; ++kk)
                bf[nh][n][kk] = frag_ld(Bb, brb + (nh * 2 + n) * 16, kk * 32 + kg, sw);
    };

    // ---- prologue: tile0 full -> buf0; tile1 {B-lo, B-hi, A-lo} -> buf1
    stage(Aglob, ldsA0, 0, 0);
    stage(Aglob, ldsA0, 1, 0);
    stage(Bglob, ldsB0, 0, 0);
    stage(Bglob, ldsB0, 1, 0);
    stage(Bglob, ldsB1, 0, BK);
    stage(Bglob, ldsB1, 1, BK);
    stage(Aglob, ldsA1, 0, BK);
    asm volatile("s_waitcnt vmcnt(6)" ::: "memory");  // tile0 landed; 3 ht in flight
    __builtin_amdgcn_s_barrier();

    for (int t = 0; t < NT; t += 2) {
        const int kt1 = (t + 1) * BK, kt2 = (t + 2) * BK, kt3 = (t + 3) * BK;
        const bool p2 = (t + 2 < NT), p3 = (t + 3 < NT);

        // P1: reads phi1(buf0): bf(nh0)+af(mh0); stage A-hi(t+1)->buf1
        readBF(ldsB0, 0);
        readAF(ldsA0, 0);
        stage(Aglob, ldsA1, 1, kt1);
        __builtin_amdgcn_s_barrier();
        LGKM0_SB;
        __builtin_amdgcn_s_setprio(1);
        mfma_phase<0, 0>(acc, af, bf);
        __builtin_amdgcn_s_setprio(0);
        __builtin_amdgcn_s_barrier();

        // P2: reads bf(nh1) from buf0
        readBF(ldsB0, 1);
        __builtin_amdgcn_s_barrier();
        LGKM0_SB;
        __builtin_amdgcn_s_setprio(1);
        mfma_phase<0, 1>(acc, af, bf);
        __builtin_amdgcn_s_setprio(0);
        __builtin_amdgcn_s_barrier();

        // P3: reads af(mh1) from buf0; stage B-lo(t+2)->buf0 (B retired at P2)
        readAF(ldsA0, 1);
        if (p2) stage(Bglob, ldsB0, 0, kt2);
        __builtin_amdgcn_s_barrier();
        LGKM0_SB;
        __builtin_amdgcn_s_setprio(1);
        mfma_phase<1, 0>(acc, af, bf);
        __builtin_amdgcn_s_setprio(0);
        __builtin_amdgcn_s_barrier();

        // P4: no reads; stage B-hi(t+2)+A-lo(t+2)->buf0 (A retired at P3);
        //     counted vmcnt: leaves P3+P4's 3 half-tiles, forces tile t+1 landed
        if (p2) {
            stage(Bglob, ldsB0, 1, kt2);
            stage(Aglob, ldsA0, 0, kt2);
        }
        __builtin_amdgcn_s_barrier();
        __builtin_amdgcn_s_setprio(1);
        mfma_phase<1, 1>(acc, af, bf);
        __builtin_amdgcn_s_setprio(0);
        if (p2) {
            asm volatile("s_waitcnt vmcnt(6)" ::: "memory");
        } else {
            asm volatile("s_waitcnt vmcnt(0)" ::: "memory");  // tail: force A-hi(t+1)
        }
        __builtin_amdgcn_s_barrier();

        // P5: reads phi1(buf1); stage A-hi(t+2)->buf0
        readBF(ldsB1, 0);
        readAF(ldsA1, 0);
        if (p2) stage(Aglob, ldsA0, 1, kt2);
        __builtin_amdgcn_s_barrier();
        LGKM0_SB;
        __builtin_amdgcn_s_setprio(1);
        mfma_phase<0, 0>(acc, af, bf);
        __builtin_amdgcn_s_setprio(0);
        __builtin_amdgcn_s_barrier();

        // P6: reads bf(nh1) from buf1
        readBF(ldsB1, 1);
        __builtin_amdgcn_s_barrier();
        LGKM0_SB;
        __builtin_amdgcn_s_setprio(1);
        mfma_phase<0, 1>(acc, af, bf);
        __builtin_amdgcn_s_setprio(0);
        __builtin_amdgcn_s_barrier();

        // P7: reads af(mh1) from buf1; stage B-lo(t+3)->buf1
        readAF(ldsA1, 1);
        if (p3) stage(Bglob, ldsB1, 0, kt3);
        __builtin_amdgcn_s_barrier();
        LGKM0_SB;
        __builtin_amdgcn_s_setprio(1);
        mfma_phase<1, 0>(acc, af, bf);
        __builtin_amdgcn_s_setprio(0);
        __builtin_amdgcn_s_barrier();

        // P8: stage B-hi(t+3)+A-lo(t+3)->buf1; vmcnt(6) forces tile t+2 landed
        if (p3) {
            stage(Bglob, ldsB1, 1, kt3);
            stage(Aglob, ldsA1, 0, kt3);
        }
        __builtin_amdgcn_s_barrier();
        __builtin_amdgcn_s_setprio(1);
        mfma_phase<1, 1>(acc, af, bf);
        __builtin_amdgcn_s_setprio(0);
        asm volatile("s_waitcnt vmcnt(6)" ::: "memory");
        __builtin_amdgcn_s_barrier();
    }

    // epilogue: D row = (lane>>4)*4 + j (A side), col = lane&15 (B side)
    const int rg = (lane >> 4) * 4;
#pragma unroll
    for (int n = 0; n < 4; ++n) {
        int col = brow0 + wc * 64 + n * 16 + rl;
        float bv = bias[col];
#pragma unroll
        for (int m = 0; m < 8; ++m) {
            int rowb = arow0 + wr * 128 + m * 16 + rg;
#pragma unroll
            for (int j = 0; j < 4; ++j)
                C[(size_t)(rowb + j) * N + col] = acc[m][n][j] + bv;
        }
    }
}

extern "C" void kernel_launch(void* const* d_in, const int* in_sizes, int n_in,
                              void* d_out, int out_size, void* d_ws, size_t ws_size,
                              hipStream_t stream) {
    const float* x = (const float*)d_in[0];     // [M,K]
    const float* w = (const float*)d_in[1];     // [N,K]
    const float* bias = (const float*)d_in[2];  // [N]
    float* out = (float*)d_out;

    const int N = in_sizes[2];                 // 16384
    const int K = in_sizes[1] / N;             // 4096
    const int M = in_sizes[0] / K;             // 8192

    short* xq = (short*)d_ws;
    short* wq = xq + (size_t)M * K;

    int nx4 = M * K / 4;
    int nw4 = N * K / 4;
    quant_kernel<<<(nx4 + 255) / 256, 256, 0, stream>>>(
        (const float4*)x, (ushort4*)xq, nx4);
    quant_kernel<<<(nw4 + 255) / 256, 256, 0, stream>>>(
        (const float4*)w, (ushort4*)wq, nw4);

    hipFuncSetAttribute((const void*)gemm8p,
                        hipFuncAttributeMaxDynamicSharedMemorySize, 131072);

    int nwg = (M / BM) * (N / BN);  // 32*64 = 2048, %8==0
    gemm8p<<<nwg, 512, 131072, stream>>>(
        (const short*)xq, (const short*)wq, bias, out, M, N, K);
}